// Round 1
// baseline (3144.416 us; speedup 1.0000x reference)
//
#include <hip/hip_runtime.h>
#include <cstdint>

// Problem constants
// B=32, C=32, O=32, N=512, L=128, K=2, DIL=2, PAD=2, EPS=1e-5
// x: (B,C,N,L) fp32. Outputs: residual (B,C,N,L) then skip (B,O,N,L), fp32.

typedef unsigned short ushort_t;
typedef unsigned int uint_t;

__device__ __forceinline__ float bf2f(uint_t u) {
  return __uint_as_float(u << 16);
}
__device__ __forceinline__ ushort_t f2bf(float f) {
  uint_t u = __float_as_uint(f);
  u += 0x7fffu + ((u >> 16) & 1u);   // RNE
  return (ushort_t)(u >> 16);
}

// ---------------------------------------------------------------------------
// K0: fold gc_w0/gc_w1/gc_b into skip/res weights.
//   A0s[o][c] = sum_k skip_w[o][k]*gc_w0[k][c]   (and A1s with gc_w1)
//   A0r/A1r likewise with res_w.
//   bs[o] = skip_w@gc_b + skip_b ; br[c] = res_w@gc_b + res_b
// Wc layout (floats): [0:1024)=A0s [1024:2048)=A1s [2048:3072)=A0r
//   [3072:4096)=A1r [4096:4128)=bs [4128:4160)=br [4160:4192)=bn_sum
//   [4192:4224)=bn_sq   (bn slots written by k2b)
// ---------------------------------------------------------------------------
__global__ __launch_bounds__(256) void k0(
    const float* __restrict__ gc_w0, const float* __restrict__ gc_w1,
    const float* __restrict__ gc_b, const float* __restrict__ skip_w,
    const float* __restrict__ skip_b, const float* __restrict__ res_w,
    const float* __restrict__ res_b, float* __restrict__ Wc) {
  const int t = threadIdx.x;
  for (int e = t; e < 4096; e += 256) {
    const int mat = e >> 10, idx = e & 1023, o = idx >> 5, ci = idx & 31;
    const float* left = (mat < 2) ? skip_w : res_w;
    const float* g = (mat & 1) ? gc_w1 : gc_w0;
    float s = 0.f;
    #pragma unroll
    for (int c = 0; c < 32; ++c) s = fmaf(left[o * 32 + c], g[c * 32 + ci], s);
    Wc[mat * 1024 + idx] = s;
  }
  if (t < 32) {
    float s = 0.f, r = 0.f;
    #pragma unroll
    for (int c = 0; c < 32; ++c) {
      s = fmaf(skip_w[t * 32 + c], gc_b[c], s);
      r = fmaf(res_w[t * 32 + c], gc_b[c], r);
    }
    Wc[4096 + t] = s + skip_b[t];
    Wc[4128 + t] = r + res_b[t];
  }
}

// ---------------------------------------------------------------------------
// K1a: transpose x (B,C,N,L) fp32 -> xT[b][l][c][n] bf16 (node index fastest).
// One block per (n-tile of 64, c, b). LDS tile [l][n] pitch 65 (conflict-free
// transposed reads).
// ---------------------------------------------------------------------------
__global__ __launch_bounds__(256) void k1a(const float* __restrict__ x,
                                           ushort_t* __restrict__ xT) {
  __shared__ float tile[128 * 65];
  const int nt = blockIdx.x, c = blockIdx.y, b = blockIdx.z;
  const int n0 = nt * 64, t = threadIdx.x;
  const int lq = t & 31, r = t >> 5;  // lanes -> l (coalesced global reads)
  const float* src = x + (((size_t)(b * 32 + c)) * 512 + n0) * 128;
  for (int nr = 0; nr < 8; ++nr) {
    const int nn = nr * 8 + r;
    const float4 v = *(const float4*)(src + nn * 128 + lq * 4);
    tile[(lq * 4 + 0) * 65 + nn] = v.x;
    tile[(lq * 4 + 1) * 65 + nn] = v.y;
    tile[(lq * 4 + 2) * 65 + nn] = v.z;
    tile[(lq * 4 + 3) * 65 + nn] = v.w;
  }
  __syncthreads();
  const int nn2 = t & 63, lg = t >> 6;
  ushort_t* dst = xT + (size_t)b * 128 * 16384 + (size_t)c * 512 + n0 + nn2;
  for (int i = 0; i < 32; ++i) {
    const int l = lg * 32 + i;
    dst[(size_t)l * 16384] = f2bf(tile[l * 65 + nn2]);
  }
}

// ---------------------------------------------------------------------------
// K1: gated causal dilated conv. h[b][l][o][n] (bf16, n fastest) =
//   tanh(conv_filt) * sigmoid(conv_gate), taps at l-2 and l.
// Block per (l, b); lanes -> n (coalesced). Weights are wave-uniform -> SGPR.
// ---------------------------------------------------------------------------
__global__ __launch_bounds__(256) void k1(
    const ushort_t* __restrict__ xT, const float* __restrict__ fw,
    const float* __restrict__ fb, const float* __restrict__ gw,
    const float* __restrict__ gb, ushort_t* __restrict__ hA) {
  const int l = blockIdx.x, b = blockIdx.y;
  const int t = threadIdx.x;
  const size_t plane = (size_t)(b * 128 + l) * 16384;
  const size_t planem2 = (size_t)(b * 128 + l - 2) * 16384;
  for (int half = 0; half < 2; ++half) {
    const int n = t + half * 256;
    float x0v[32], xmv[32];
    #pragma unroll
    for (int c = 0; c < 32; ++c) {
      x0v[c] = bf2f(xT[plane + c * 512 + n]);
      xmv[c] = (l >= 2) ? bf2f(xT[planem2 + c * 512 + n]) : 0.f;
    }
    #pragma unroll 4
    for (int o = 0; o < 32; ++o) {
      float f = fb[o], g = gb[o];
      #pragma unroll
      for (int c = 0; c < 32; ++c) {
        const float w0 = fw[(o * 32 + c) * 2], w1 = fw[(o * 32 + c) * 2 + 1];
        f = fmaf(w0, xmv[c], fmaf(w1, x0v[c], f));
        const float u0 = gw[(o * 32 + c) * 2], u1 = gw[(o * 32 + c) * 2 + 1];
        g = fmaf(u0, xmv[c], fmaf(u1, x0v[c], g));
      }
      const float e2f = __expf(2.f * f);
      const float th = 1.f - 2.f / (e2f + 1.f);     // tanh, overflow-safe
      const float sg = 1.f / (1.f + __expf(-g));    // sigmoid
      hA[plane + o * 512 + n] = f2bf(th * sg);
    }
  }
}

// ---------------------------------------------------------------------------
// K2: graph conv. Per b: G0T/G1T[(l,c)][n] = sum_m h[b][m][c][l]*S{0,1}[n][m].
//   A-operand = hA[b][j][m] (j=l*32+c, m contiguous, bf16)
//   B-operand = S[n][m] (m contiguous, fp32)
// Tile: 128(j) x 64(n), K-step 16, 8x4 microtile, 2 accumulator sets.
// Epilogue folds channel mixes (A0s..A1r), writes skip_raw/res_raw bf16 in
// [b][l][ch][n] layout + per-channel BN partial sums (deterministic).
// ---------------------------------------------------------------------------
__global__ __launch_bounds__(256) void k2(
    const ushort_t* __restrict__ hA, const float* __restrict__ S0,
    const float* __restrict__ S1, const float* __restrict__ Wc,
    ushort_t* __restrict__ skip_raw, ushort_t* __restrict__ res_raw,
    float* __restrict__ part) {
  __shared__ float sm[4352];
  float* a_s = sm;           // [16][132]  main-loop staging
  float* b0_s = sm + 2112;   // [16][68]
  float* b1_s = sm + 3200;   // [16][68]
  float* g0_s = sm;          // [32][68]   epilogue (aliases staging)
  float* g1_s = sm + 2176;

  const int t = threadIdx.x;
  const int nt = blockIdx.x, jt = blockIdx.y, b = blockIdx.z;
  const int n0 = nt * 64, j0 = jt * 128;
  const int tj = t >> 4, tn = t & 15;

  float g0[8][4], g1[8][4];
  #pragma unroll
  for (int r = 0; r < 8; ++r)
    #pragma unroll
    for (int i = 0; i < 4; ++i) { g0[r][i] = 0.f; g1[r][i] = 0.f; }

  const ushort_t* hAb = hA + (size_t)b * 4096 * 512;
  const int ja = t >> 1, ha = (t & 1) * 8;  // A staging: row, k-offset
  const int nb = t >> 2, kb = (t & 3) * 4;  // B staging: row, k-offset

  for (int m0 = 0; m0 < 512; m0 += 16) {
    __syncthreads();
    {  // stage A (128 rows x 16 k, bf16 -> fp32, transposed to [k][j])
      const uint4 v = *(const uint4*)(hAb + (size_t)(j0 + ja) * 512 + m0 + ha);
      float* d = a_s + ja;
      uint_t w;
      w = v.x; d[(ha + 0) * 132] = bf2f(w & 0xffffu); d[(ha + 1) * 132] = bf2f(w >> 16);
      w = v.y; d[(ha + 2) * 132] = bf2f(w & 0xffffu); d[(ha + 3) * 132] = bf2f(w >> 16);
      w = v.z; d[(ha + 4) * 132] = bf2f(w & 0xffffu); d[(ha + 5) * 132] = bf2f(w >> 16);
      w = v.w; d[(ha + 6) * 132] = bf2f(w & 0xffffu); d[(ha + 7) * 132] = bf2f(w >> 16);
    }
    {  // stage B0/B1 (64 rows x 16 k fp32, transposed to [k][n])
      const float4 v0 = *(const float4*)(S0 + (size_t)(n0 + nb) * 512 + m0 + kb);
      b0_s[(kb + 0) * 68 + nb] = v0.x; b0_s[(kb + 1) * 68 + nb] = v0.y;
      b0_s[(kb + 2) * 68 + nb] = v0.z; b0_s[(kb + 3) * 68 + nb] = v0.w;
      const float4 v1 = *(const float4*)(S1 + (size_t)(n0 + nb) * 512 + m0 + kb);
      b1_s[(kb + 0) * 68 + nb] = v1.x; b1_s[(kb + 1) * 68 + nb] = v1.y;
      b1_s[(kb + 2) * 68 + nb] = v1.z; b1_s[(kb + 3) * 68 + nb] = v1.w;
    }
    __syncthreads();
    #pragma unroll
    for (int k = 0; k < 16; ++k) {
      const float4 b0v = *(const float4*)(b0_s + k * 68 + tn * 4);
      const float4 b1v = *(const float4*)(b1_s + k * 68 + tn * 4);
      const float4 aL = *(const float4*)(a_s + k * 132 + tj * 8);
      const float4 aH = *(const float4*)(a_s + k * 132 + tj * 8 + 4);
      const float av[8] = {aL.x, aL.y, aL.z, aL.w, aH.x, aH.y, aH.z, aH.w};
      const float b0a[4] = {b0v.x, b0v.y, b0v.z, b0v.w};
      const float b1a[4] = {b1v.x, b1v.y, b1v.z, b1v.w};
      #pragma unroll
      for (int r = 0; r < 8; ++r)
        #pragma unroll
        for (int i = 0; i < 4; ++i) {
          g0[r][i] = fmaf(av[r], b0a[i], g0[r][i]);
          g1[r][i] = fmaf(av[r], b1a[i], g1[r][i]);
        }
    }
  }
  __syncthreads();  // main-loop LDS dead; epilogue aliases it

  const float* A0s = Wc;
  const float* A1s = Wc + 1024;
  const float* A0r = Wc + 2048;
  const float* A1r = Wc + 3072;
  const float* bsv = Wc + 4096;
  const float* brv = Wc + 4128;
  const int n_i = t & 63, og = t >> 6;  // og = wave id (uniform)
  float accs[8], accq[8];
  #pragma unroll
  for (int oi = 0; oi < 8; ++oi) { accs[oi] = 0.f; accq[oi] = 0.f; }

  for (int lg = 0; lg < 4; ++lg) {  // l-group = 32 tile rows = one wave's rows
    if ((tj >> 2) == lg) {
      const int c0 = (tj & 3) * 8;
      #pragma unroll
      for (int r = 0; r < 8; ++r) {
        *(float4*)(g0_s + (c0 + r) * 68 + tn * 4) =
            make_float4(g0[r][0], g0[r][1], g0[r][2], g0[r][3]);
        *(float4*)(g1_s + (c0 + r) * 68 + tn * 4) =
            make_float4(g1[r][0], g1[r][1], g1[r][2], g1[r][3]);
      }
    }
    __syncthreads();
    float sk[8], rs[8];
    #pragma unroll
    for (int oi = 0; oi < 8; ++oi) {
      sk[oi] = bsv[og * 8 + oi];
      rs[oi] = brv[og * 8 + oi];
    }
    for (int c = 0; c < 32; ++c) {
      const float v0 = g0_s[c * 68 + n_i];
      const float v1 = g1_s[c * 68 + n_i];
      #pragma unroll
      for (int oi = 0; oi < 8; ++oi) {
        const int o = og * 8 + oi;
        sk[oi] = fmaf(A0s[o * 32 + c], v0, fmaf(A1s[o * 32 + c], v1, sk[oi]));
        rs[oi] = fmaf(A0r[o * 32 + c], v0, fmaf(A1r[o * 32 + c], v1, rs[oi]));
      }
    }
    const int l = jt * 4 + lg;
    const size_t base = ((size_t)((b * 128 + l) * 32)) * 512 + n0 + n_i;
    #pragma unroll
    for (int oi = 0; oi < 8; ++oi) {
      const int o = og * 8 + oi;
      skip_raw[base + (size_t)o * 512] = f2bf(sk[oi]);
      res_raw[base + (size_t)o * 512] = f2bf(rs[oi]);
      accs[oi] += rs[oi];
      accq[oi] = fmaf(rs[oi], rs[oi], accq[oi]);
    }
    __syncthreads();
  }

  // per-wave lane reduction, one partial per (block, channel) — no atomics
  const int bidx = (b * 32 + jt) * 8 + nt;
  #pragma unroll
  for (int oi = 0; oi < 8; ++oi) {
    float s = accs[oi], q = accq[oi];
    for (int m = 1; m < 64; m <<= 1) {
      s += __shfl_xor(s, m, 64);
      q += __shfl_xor(q, m, 64);
    }
    if (n_i == 0) {
      part[(size_t)(og * 8 + oi) * 8192 + bidx] = s;
      part[(size_t)(32 + og * 8 + oi) * 8192 + bidx] = q;
    }
  }
}

// ---------------------------------------------------------------------------
// K2b: reduce BN partials -> Wc[4160+c] (sum), Wc[4192+c] (sumsq)
// ---------------------------------------------------------------------------
__global__ __launch_bounds__(256) void k2b(const float* __restrict__ part,
                                           float* __restrict__ Wc) {
  const int row = blockIdx.x;
  const int t = threadIdx.x;
  float s = 0.f;
  for (int i = t; i < 8192; i += 256) s += part[(size_t)row * 8192 + i];
  for (int m = 1; m < 64; m <<= 1) s += __shfl_xor(s, m, 64);
  __shared__ float red[4];
  if ((t & 63) == 0) red[t >> 6] = s;
  __syncthreads();
  if (t == 0) Wc[4160 + row] = red[0] + red[1] + red[2] + red[3];
}

// ---------------------------------------------------------------------------
// K3: transpose [b][l][ch][n] -> [b][ch][n][l]; BN + x-residual for res,
// passthrough for skip. Coalesced both sides via LDS (pitch 129).
// blockIdx.z = b*2 + tensor (0=res->residual, 1=skip).
// ---------------------------------------------------------------------------
__global__ __launch_bounds__(256) void k3(
    const ushort_t* __restrict__ skip_raw, const ushort_t* __restrict__ res_raw,
    const float* __restrict__ x, const float* __restrict__ Wc,
    const float* __restrict__ gamma, const float* __restrict__ beta,
    float* __restrict__ out) {
  __shared__ float tile[64 * 129];
  const int nt = blockIdx.x, ch = blockIdx.y, z = blockIdx.z;
  const int b = z >> 1, tensor = z & 1;
  const int n0 = nt * 64, t = threadIdx.x;
  const ushort_t* src = tensor ? skip_raw : res_raw;
  const int nn = t & 63, lg = t >> 6;
  const size_t sbase = (size_t)(b * 128) * 16384 + (size_t)ch * 512 + n0 + nn;
  for (int i = 0; i < 32; ++i) {
    const int l = lg * 32 + i;
    tile[nn * 129 + l] = bf2f(src[sbase + (size_t)l * 16384]);
  }
  __syncthreads();
  float scale = 1.f, shift = 0.f;
  if (tensor == 0) {
    const float s = Wc[4160 + ch], q = Wc[4192 + ch];
    const float mean = s * (1.f / 2097152.f);
    const float var = q * (1.f / 2097152.f) - mean * mean;
    scale = gamma[ch] * rsqrtf(var + 1e-5f);
    shift = beta[ch] - mean * scale;
  }
  const int l_ = t & 127, ng = t >> 7;
  float* dst = out + (tensor ? 67108864u : 0u);
  for (int j = 0; j < 32; ++j) {
    const int nq = ng * 32 + j;
    float v = tile[nq * 129 + l_] * scale + shift;
    const size_t idx = ((size_t)(b * 32 + ch) * 512 + n0 + nq) * 128 + l_;
    if (tensor == 0) v += x[idx];
    dst[idx] = v;
  }
}

// ---------------------------------------------------------------------------
extern "C" void kernel_launch(void* const* d_in, const int* in_sizes, int n_in,
                              void* d_out, int out_size, void* d_ws,
                              size_t ws_size, hipStream_t stream) {
  const float* x = (const float*)d_in[0];
  const float* S0 = (const float*)d_in[1];
  const float* S1 = (const float*)d_in[2];
  const float* fw = (const float*)d_in[3];
  const float* fb = (const float*)d_in[4];
  const float* gw = (const float*)d_in[5];
  const float* gb = (const float*)d_in[6];
  const float* gc_w0 = (const float*)d_in[7];
  const float* gc_w1 = (const float*)d_in[8];
  const float* gc_b = (const float*)d_in[9];
  const float* skip_w = (const float*)d_in[10];
  const float* skip_b = (const float*)d_in[11];
  const float* res_w = (const float*)d_in[12];
  const float* res_b = (const float*)d_in[13];
  const float* gamma = (const float*)d_in[14];
  const float* beta = (const float*)d_in[15];
  float* out = (float*)d_out;

  char* ws = (char*)d_ws;
  // ws layout: [0,32768) Wc | hA 134MB | xT/skip_raw 134MB | res_raw 134MB |
  //            part 2MB.  Total ~405MB.
  float* Wc = (float*)ws;
  ushort_t* hA = (ushort_t*)(ws + 32768);
  ushort_t* xT = (ushort_t*)(ws + 32768 + 134217728ull);  // reused as skip_raw
  ushort_t* res_raw = (ushort_t*)(ws + 32768 + 2ull * 134217728ull);
  float* part = (float*)(ws + 32768 + 3ull * 134217728ull);

  k0<<<1, 256, 0, stream>>>(gc_w0, gc_w1, gc_b, skip_w, skip_b, res_w, res_b,
                            Wc);
  k1a<<<dim3(8, 32, 32), 256, 0, stream>>>(x, xT);
  k1<<<dim3(128, 32), 256, 0, stream>>>(xT, fw, fb, gw, gb, hA);
  k2<<<dim3(8, 32, 32), 256, 0, stream>>>(hA, S0, S1, Wc, xT /*skip_raw*/,
                                          res_raw, part);
  k2b<<<64, 256, 0, stream>>>(part, Wc);
  k3<<<dim3(8, 32, 64), 256, 0, stream>>>(xT /*skip_raw*/, res_raw, x, Wc,
                                          gamma, beta, out);
}